// Round 13
// baseline (4125.928 us; speedup 1.0000x reference)
//
#include <hip/hip_runtime.h>
#include <hip/hip_bf16.h>

typedef __hip_bfloat16 bf16;
typedef unsigned short u16;
typedef unsigned int u32;
typedef __attribute__((ext_vector_type(8))) short bf16x8;
typedef __attribute__((ext_vector_type(4))) float f32x4;

// Problem constants
#define BATCH 256
#define TLEN 100
#define HDIM 1024
#define G4 4096
#define OUT_HT (BATCH * TLEN * HDIM)    // float offset of c4 section in d_out

// Workspace layout (byte offsets).
#define WS_WP 0u
#define WS_BIAS 59244544u   // f32 [4][4096]
#define WS_XT 59310080u     // bf16 chunk-major [100][256][64], swizzle baked
#define WS_H 62586880u      // bf16 [8 slots][16 chunks][256][64], swizzle baked
#define WS_FLAGS (WS_H + 4194304u)  // u32 [4 layers][2 btiles][32 slices]

__device__ __forceinline__ float sigm(float x) { return 1.0f / (1.0f + __expf(-x)); }
__device__ __forceinline__ float tanh_(float x) { return 2.0f / (1.0f + __expf(-2.0f * x)) - 1.0f; }

// ---------- setup kernels (unchanged, proven) ----------

__global__ void pack_w(const float* __restrict__ wih, const float* __restrict__ whh,
                       bf16* __restrict__ dst, int NC, int din) {
  int i = blockIdx.x * 256 + threadIdx.x;
  if (i >= 32 * NC * 128 * 64) return;
  int k6 = i & 63;
  int r = (i >> 6) & 127;
  int jc = i >> 13;
  int c = jc % NC;
  int j = jc / NC;
  int grow = ((r >> 5) << 10) + j * 32 + (r & 31);
  int k = c * 64 + k6;
  float v = (k < din) ? wih[grow * din + k] : whh[(grow << 10) + (k - din)];
  dst[(jc << 13) + (r << 6) + (k6 ^ ((r & 7) << 3))] = __float2bfloat16(v);
}

__global__ void pack_bias(const float* __restrict__ a, const float* __restrict__ b,
                          float* __restrict__ dst) {
  int i = blockIdx.x * 256 + threadIdx.x;
  if (i < G4) dst[i] = a[i] + b[i];
}

__global__ void pack_x(const float* __restrict__ x, bf16* __restrict__ xT) {
  int i = blockIdx.x * 256 + threadIdx.x;
  if (i >= TLEN * BATCH * 64) return;
  int k = i & 63;
  int b = (i >> 6) & 255;
  int t = i >> 14;
  xT[(t << 14) + (b << 6) + (k ^ ((b & 7) << 3))] = __float2bfloat16(x[(b * TLEN + t) * 64 + k]);
}

// ---------- main persistent kernel: register-direct GEMM, manual 3-buffer pipeline ----------
// R12 chassis (256 WGs x 512 thr coop, zero K-loop barriers, G0/G1 epilogue, flags).
// ONLY change: K-loop hand-pipelined. Three named fragment buffers F0/F1/F2; prologue
// loads chunks 0,1; steady state LOAD(F[(c+2)%3]) then MFMA(F[c%3]) via 3x-unrolled
// loop. NC in {17,32}, both == 2 (mod 3) -> loop "for(c=0;c+2<NC;c+=3)" + 2-chunk tail,
// all load indices < NC (no clamping). At each MFMA group 16 younger loads in flight
// -> ~2 chunk-periods of L2-latency cover. ~96 extra VGPRs hold the pipeline.

#define LOADF(Fa, Fb, c_) do {                                                  \
    int c__ = (c_);                                                             \
    const char* aI_ = (c__ < T0) ? (aB0 + (u32)c__ * 32768u)                    \
                                 : (aB1 + (u32)(c__ - T0) * 32768u);            \
    const char* bI_ = Wbytes + (u32)c__ * 16384u;                               \
    _Pragma("unroll")                                                           \
    for (int q_ = 0; q_ < 4; ++q_) Fa[q_] = *(const bf16x8*)(aI_ + aOff[q_]);   \
    _Pragma("unroll")                                                           \
    for (int q_ = 0; q_ < 4; ++q_) Fb[q_] = *(const bf16x8*)(bI_ + bOff[q_]);   \
  } while (0)

#define MFMAF(Fa, Fb) do {                                                      \
    _Pragma("unroll")                                                           \
    for (int mt_ = 0; mt_ < 4; ++mt_)                                           \
      _Pragma("unroll")                                                         \
      for (int nt_ = 0; nt_ < 4; ++nt_)                                         \
        acc[mt_][nt_] = __builtin_amdgcn_mfma_f32_16x16x32_bf16(                \
            Fa[mt_], Fb[nt_], acc[mt_][nt_], 0, 0, 0);                          \
  } while (0)

__global__ void __launch_bounds__(512, 2)
lstm_main(const u16* __restrict__ Wp, const float* __restrict__ biasc,
          const u16* __restrict__ xT, u16* __restrict__ hbuf,
          float* __restrict__ out, u32* __restrict__ flags) {
  __shared__ float G0[128 * 132];   // 67584 B
  __shared__ float G1[128 * 132];   // 67584 B

  const int tid = threadIdx.x;
  const int lane = tid & 63;
  const int wave = tid >> 6;
  const int wg = blockIdx.x;
  const int layer = (wg & 127) >> 5;
  const int j = wg & 31;
  const int bt = wg >> 7;
  const int b0 = bt * 128;
  const int h0 = j * 32;

  const int NC = (layer == 0) ? 17 : 32;   // 17%3==2, 32%3==2
  const int T0 = (layer == 0) ? 1 : 16;
  const char* Wbytes = (const char*)(Wp
                       + ((layer == 0) ? 0u : (4456448u + (u32)(layer - 1) * 8388608u))
                       + (u32)j * (u32)NC * 8192u);

  const int nn = tid & 31;
  float bias_r[4];
#pragma unroll
  for (int g = 0; g < 4; ++g) bias_r[g] = biasc[layer * G4 + g * HDIM + h0 + nn];

  const int r0 = (tid >> 5) * 8;
  float cst[8];
#pragma unroll
  for (int k = 0; k < 8; ++k) cst[k] = 0.0f;

  // wave grid: 2m x 2n x 2k split-K; fragment global byte offsets (R12, verified)
  const int mh = (wave >> 2) & 1;
  const int nh = (wave >> 1) & 1;
  const int kh = wave & 1;
  const int lrow = lane & 15;
  const int lswz = (lane & 7) << 4;
  const int kslot = (lane >> 4) << 4;
  const int kx = (kh * 64 + kslot) ^ lswz;

  u32 aOff[4], bOff[4];
#pragma unroll
  for (int mt = 0; mt < 4; ++mt)
    aOff[mt] = (u32)(b0 + mh * 64 + mt * 16 + lrow) * 128u + (u32)kx;
#pragma unroll
  for (int nt = 0; nt < 4; ++nt)
    bOff[nt] = (u32)(nh * 64 + nt * 16 + lrow) * 128u + (u32)kx;

  u32* myflag = flags + (layer * 2 + bt) * 32 + j;
  const u32 jj = lane & 31;
  const u32* pPrev = flags + (((layer > 0 ? layer - 1 : 0) * 2 + bt) * 32) + jj;
  const u32* pNext = flags + (((layer < 3 ? layer + 1 : 3) * 2 + bt) * 32) + jj;
  const u32* pOwn  = flags + ((layer * 2 + bt) * 32) + jj;

  for (int t = 0; t < TLEN; ++t) {
    // ---- dependency wait (wave 0 polls; proven R7/R8/R12) ----
    if (wave == 0) {
      const bool needP = (layer > 0) && (lane < 32);
      const bool needN = (layer < 3) && (lane < 32) && (t >= 2);
      const bool needO = (lane >= 32) && (t >= 1);
      while (true) {
        bool ok = true;
        if (needP) ok &= (__hip_atomic_load(pPrev, __ATOMIC_RELAXED, __HIP_MEMORY_SCOPE_AGENT) >= (u32)(t + 1));
        if (needN) ok &= (__hip_atomic_load(pNext, __ATOMIC_RELAXED, __HIP_MEMORY_SCOPE_AGENT) >= (u32)(t - 1));
        if (needO) ok &= (__hip_atomic_load(pOwn,  __ATOMIC_RELAXED, __HIP_MEMORY_SCOPE_AGENT) >= (u32)t);
        if (__all(ok)) break;
        __builtin_amdgcn_s_sleep(1);
      }
      __builtin_amdgcn_fence(__ATOMIC_ACQUIRE, "agent");
    }
    __syncthreads();

    // chunk image bases (image = 32768 B: [256 rows][128 B], swizzle baked)
    const char* aB0 = (layer == 0)
        ? ((const char*)xT + (u32)t * 32768u)
        : ((const char*)hbuf + (u32)((layer - 1) * 2 + (t & 1)) * 524288u);
    const char* aB1 = (const char*)hbuf + (u32)(layer * 2 + ((t + 1) & 1)) * 524288u;

    f32x4 acc[4][4];
#pragma unroll
    for (int mt = 0; mt < 4; ++mt)
#pragma unroll
      for (int nt = 0; nt < 4; ++nt) acc[mt][nt] = (f32x4)(0.0f);

    // ---- manual 3-buffer software pipeline (prefetch distance 2) ----
    bf16x8 F0a[4], F0b[4], F1a[4], F1b[4], F2a[4], F2b[4];
    LOADF(F0a, F0b, 0);
    LOADF(F1a, F1b, 1);
    for (int c = 0; c + 2 < NC; c += 3) {
      LOADF(F2a, F2b, c + 2);  MFMAF(F0a, F0b);
      LOADF(F0a, F0b, c + 3);  MFMAF(F1a, F1b);
      LOADF(F1a, F1b, c + 4);  MFMAF(F2a, F2b);
    }
    MFMAF(F0a, F0b);   // chunk NC-2
    MFMAF(F1a, F1b);   // chunk NC-1

    // gate-tile dump (disjoint per wave); barrier before cross-wave read
    float* Gw = kh ? G1 : G0;
#pragma unroll
    for (int mt = 0; mt < 4; ++mt)
#pragma unroll
      for (int nt = 0; nt < 4; ++nt) {
        int row = mh * 64 + mt * 16 + (lane >> 4) * 4;
        int col = nh * 64 + nt * 16 + (lane & 15);
#pragma unroll
        for (int r = 0; r < 4; ++r) Gw[(row + r) * 132 + col] = acc[mt][nt][r];
      }
    __syncthreads();

    // LSTM cell update; c stays in registers. Gates = G0 + G1 (K-halves) + bias.
    u16* outSlot = hbuf + (u32)(layer * 2 + (t & 1)) * 262144u;
    const int hcol = h0 + nn;
    const int j2 = hcol >> 6;
    const int colin = hcol & 63;
#pragma unroll
    for (int k = 0; k < 8; ++k) {
      int r = r0 + k;
      float gi = G0[r * 132 + nn]      + G1[r * 132 + nn]      + bias_r[0];
      float gf = G0[r * 132 + 32 + nn] + G1[r * 132 + 32 + nn] + bias_r[1];
      float gg = G0[r * 132 + 64 + nn] + G1[r * 132 + 64 + nn] + bias_r[2];
      float go = G0[r * 132 + 96 + nn] + G1[r * 132 + 96 + nn] + bias_r[3];
      float iv = sigm(gi), fv = sigm(gf), gv = tanh_(gg), ov = sigm(go);
      float cv = fv * cst[k] + iv * gv;
      cst[k] = cv;
      float hv = ov * tanh_(cv);
      int b = b0 + r;
      bf16 hb = __float2bfloat16(hv);
      outSlot[j2 * 16384 + b * 64 + (colin ^ ((b & 7) << 3))] = *(u16*)&hb;
      if (layer == 3) {
        out[((size_t)b * TLEN + t) * HDIM + hcol] = hv;
        if (t == TLEN - 1) out[OUT_HT + (size_t)b * HDIM + hcol] = cv;
      }
    }

    // ---- publish: all WG stores (and G reads) done -> release epoch ----
    __syncthreads();
    if (tid == 0)
      __hip_atomic_store(myflag, (u32)(t + 1), __ATOMIC_RELEASE, __HIP_MEMORY_SCOPE_AGENT);
  }
}

// ---------- host ----------

extern "C" void kernel_launch(void* const* d_in, const int* in_sizes, int n_in,
                              void* d_out, int out_size, void* d_ws, size_t ws_size,
                              hipStream_t stream) {
  const float* x = (const float*)d_in[0];
  const float* Wih[4] = {(const float*)d_in[1], (const float*)d_in[5],
                         (const float*)d_in[9], (const float*)d_in[13]};
  const float* Whh[4] = {(const float*)d_in[2], (const float*)d_in[6],
                         (const float*)d_in[10], (const float*)d_in[14]};
  const float* bih[4] = {(const float*)d_in[3], (const float*)d_in[7],
                         (const float*)d_in[11], (const float*)d_in[15]};
  const float* bhh[4] = {(const float*)d_in[4], (const float*)d_in[8],
                         (const float*)d_in[12], (const float*)d_in[16]};

  char* ws = (char*)d_ws;
  bf16* Wp = (bf16*)(ws + WS_WP);
  float* biasc = (float*)(ws + WS_BIAS);
  bf16* xT = (bf16*)(ws + WS_XT);
  u16* hbuf = (u16*)(ws + WS_H);
  u32* flags = (u32*)(ws + WS_FLAGS);
  float* out = (float*)d_out;

  for (int l = 0; l < 4; ++l) {
    int NC = (l == 0) ? 17 : 32;
    int din = (l == 0) ? 64 : 1024;
    bf16* dst = Wp + ((l == 0) ? 0 : (4456448 + (size_t)(l - 1) * 8388608));
    int total = 32 * NC * 128 * 64;
    pack_w<<<(total + 255) / 256, 256, 0, stream>>>(Wih[l], Whh[l], dst, NC, din);
    pack_bias<<<16, 256, 0, stream>>>(bih[l], bhh[l], biasc + l * 4096);
  }
  pack_x<<<(TLEN * BATCH * 64 + 255) / 256, 256, 0, stream>>>(x, xT);
  // zero h ring + flags
  hipMemsetAsync(ws + WS_H, 0, 4194304u + 1024u, stream);

  void* args[] = {(void*)&Wp, (void*)&biasc, (void*)&xT, (void*)&hbuf, (void*)&out, (void*)&flags};
  hipLaunchCooperativeKernel((void*)lstm_main, dim3(256), dim3(512), args, 0, stream);
}

// Round 14
// 3381.940 us; speedup vs baseline: 1.2200x; 1.2200x over previous
//
#include <hip/hip_runtime.h>
#include <hip/hip_bf16.h>

typedef __hip_bfloat16 bf16;
typedef unsigned short u16;
typedef unsigned int u32;
typedef __attribute__((ext_vector_type(8))) short bf16x8;
typedef __attribute__((ext_vector_type(4))) float f32x4;

// Problem constants
#define BATCH 256
#define TLEN 100
#define HDIM 1024
#define G4 4096
#define OUT_HT (BATCH * TLEN * HDIM)    // float offset of c4 section in d_out

// Workspace layout (byte offsets).
#define WS_WP 0u
#define WS_BIAS 59244544u   // f32 [4][4096]
#define WS_XT 59310080u     // bf16 chunk-major [100][256][64], swizzle baked
#define WS_H 62586880u      // bf16 [8 slots][16 chunks][256][64], swizzle baked
#define WS_FLAGS (WS_H + 4194304u)  // u32 [4 layers][2 btiles][32 slices]

__device__ __forceinline__ float sigm(float x) { return 1.0f / (1.0f + __expf(-x)); }
__device__ __forceinline__ float tanh_(float x) { return 2.0f / (1.0f + __expf(-2.0f * x)) - 1.0f; }

__device__ __forceinline__ void gl_lds16(const void* g, void* l) {
  __builtin_amdgcn_global_load_lds((const __attribute__((address_space(1))) u32*)g,
                                   (__attribute__((address_space(3))) u32*)l, 16, 0, 0);
}

// ---------- setup kernels (unchanged, proven) ----------

__global__ void pack_w(const float* __restrict__ wih, const float* __restrict__ whh,
                       bf16* __restrict__ dst, int NC, int din) {
  int i = blockIdx.x * 256 + threadIdx.x;
  if (i >= 32 * NC * 128 * 64) return;
  int k6 = i & 63;
  int r = (i >> 6) & 127;
  int jc = i >> 13;
  int c = jc % NC;
  int j = jc / NC;
  int grow = ((r >> 5) << 10) + j * 32 + (r & 31);
  int k = c * 64 + k6;
  float v = (k < din) ? wih[grow * din + k] : whh[(grow << 10) + (k - din)];
  dst[(jc << 13) + (r << 6) + (k6 ^ ((r & 7) << 3))] = __float2bfloat16(v);
}

__global__ void pack_bias(const float* __restrict__ a, const float* __restrict__ b,
                          float* __restrict__ dst) {
  int i = blockIdx.x * 256 + threadIdx.x;
  if (i < G4) dst[i] = a[i] + b[i];
}

__global__ void pack_x(const float* __restrict__ x, bf16* __restrict__ xT) {
  int i = blockIdx.x * 256 + threadIdx.x;
  if (i >= TLEN * BATCH * 64) return;
  int k = i & 63;
  int b = (i >> 6) & 255;
  int t = i >> 14;
  xT[(t << 14) + (b << 6) + (k ^ ((b & 7) << 3))] = __float2bfloat16(x[(b * TLEN + t) * 64 + k]);
}

// ---------- main persistent kernel ----------
// R8 chassis (256 WGs x 512 thr coop, flag sync, split-K waves, G0/G1 epilogue).
// Layers 1-3: BK=128 (16 chunks). Per chunk: A 32KB (h images 2c,2c+1) + B 32KB
//   (W images 2c,2c+1, contiguous). A ring 2 (lead 1), B ring 3 (lead 2), both
//   issued AFTER bar + lgkmcnt(0) (WAR-safe: all waves' slot reads retired before
//   any wave re-passes the barrier). Uniform vmcnt(4): at iter-c wait the only
//   ops younger than A(c) are B(c+1)'s 4.
// Layer 0: R8 BK=64 loop verbatim (17 chunks; off the critical path).

__global__ void __launch_bounds__(512, 2)
lstm_main(const u16* __restrict__ Wp, const float* __restrict__ biasc,
          const u16* __restrict__ xT, u16* __restrict__ hbuf,
          float* __restrict__ out, u32* __restrict__ flags) {
  // 160KB LDS. BK=128 path: A 2x32KB @ 0, B 3x32KB @ byte 65536 (ends 163840).
  // Layer-0 path: A 4x16KB @ 0, B 5x16KB @ byte 65536 (ends 147456).
  // Epilogue alias: G0 f32[128][132] @ 0, G1 @ byte 67584 (post-drain).
  __shared__ __align__(16) u16 smem[81920];

  const int tid = threadIdx.x;
  const int lane = tid & 63;
  const int wave = tid >> 6;
  const int wg = blockIdx.x;
  const int layer = (wg & 127) >> 5;
  const int j = wg & 31;
  const int bt = wg >> 7;
  const int b0 = bt * 128;
  const int h0 = j * 32;

  const int NC64 = (layer == 0) ? 17 : 32;
  const u16* Wsl = Wp + ((layer == 0) ? 0u : (4456448u + (u32)(layer - 1) * 8388608u))
                 + (u32)j * (u32)NC64 * 8192u;

  const int nn = tid & 31;
  float bias_r[4];
#pragma unroll
  for (int g = 0; g < 4; ++g) bias_r[g] = biasc[layer * G4 + g * HDIM + h0 + nn];

  const int r0 = (tid >> 5) * 8;
  float cst[8];
#pragma unroll
  for (int k = 0; k < 8; ++k) cst[k] = 0.0f;

  const int opu0 = wave * 1024 + lane * 8;   // u16 units (2 ops x 1KB per wave per 16KB)
  const int opu1 = opu0 + 512;

  // split-K wave grid (proven R6-R8)
  const int mh = (wave >> 2) & 1;
  const int nh = (wave >> 1) & 1;
  const int kh = wave & 1;
  const int lrow = lane & 15;
  const int lswz = (lane & 7) << 4;
  const int kslot = (lane >> 4) << 4;
  const int kx64 = (kh * 64 + kslot) ^ lswz;   // layer-0 (BK=64) read col

  float* G0 = (float*)smem;                     // [128][132]
  float* G1 = (float*)((char*)smem + 67584);    // [128][132]

  u32* myflag = flags + (layer * 2 + bt) * 32 + j;
  const u32 jj = lane & 31;
  const u32* pPrev = flags + (((layer > 0 ? layer - 1 : 0) * 2 + bt) * 32) + jj;
  const u32* pNext = flags + (((layer < 3 ? layer + 1 : 3) * 2 + bt) * 32) + jj;
  const u32* pOwn  = flags + ((layer * 2 + bt) * 32) + jj;

  for (int t = 0; t < TLEN; ++t) {
    // ---- dependency wait (wave 0 polls; proven R7/R8) ----
    if (wave == 0) {
      const bool needP = (layer > 0) && (lane < 32);
      const bool needN = (layer < 3) && (lane < 32) && (t >= 2);
      const bool needO = (lane >= 32) && (t >= 1);
      while (true) {
        bool ok = true;
        if (needP) ok &= (__hip_atomic_load(pPrev, __ATOMIC_RELAXED, __HIP_MEMORY_SCOPE_AGENT) >= (u32)(t + 1));
        if (needN) ok &= (__hip_atomic_load(pNext, __ATOMIC_RELAXED, __HIP_MEMORY_SCOPE_AGENT) >= (u32)(t - 1));
        if (needO) ok &= (__hip_atomic_load(pOwn,  __ATOMIC_RELAXED, __HIP_MEMORY_SCOPE_AGENT) >= (u32)t);
        if (__all(ok)) break;
        __builtin_amdgcn_s_sleep(1);
      }
      __builtin_amdgcn_fence(__ATOMIC_ACQUIRE, "agent");
    }
    __syncthreads();

    f32x4 acc[4][4];
#pragma unroll
    for (int mt = 0; mt < 4; ++mt)
#pragma unroll
      for (int nt = 0; nt < 4; ++nt) acc[mt][nt] = (f32x4)(0.0f);

    if (layer == 0) {
      // ======== layer 0: R8 BK=64 path, verbatim ========
      const u16* aBase0 = xT + (u32)t * 16384u + b0 * 64;
      const u16* aBase1 = hbuf + (u32)(0 * 2 + ((t + 1) & 1)) * 262144u + b0 * 64;

      auto issueA = [&](int c, int slot) {
        const u16* src = (c < 1) ? aBase0 : (aBase1 + (u32)(c - 1) * 16384u);
        gl_lds16(src + opu0, smem + slot * 8192 + wave * 1024);
        gl_lds16(src + opu1, smem + slot * 8192 + wave * 1024 + 512);
      };
      auto issueB = [&](int c, int slot) {
        const u16* src = Wsl + (u32)c * 8192u;
        gl_lds16(src + opu0, smem + 32768 + slot * 8192 + wave * 1024);
        gl_lds16(src + opu1, smem + 32768 + slot * 8192 + wave * 1024 + 512);
      };

      issueB(0, 0);
      issueA(0, 0);
      issueB(1, 1);
      issueA(1, 1);
      issueB(2, 2);

      for (int c = 0; c < 17; ++c) {
        {
          int ca = c + 2; int cca = (ca < 17) ? ca : 16;
          issueA(cca, ca & 3);
          int cb = c + 3; int ccb = (cb < 17) ? cb : 16;
          issueB(ccb, cb % 5);
        }
        asm volatile("s_waitcnt vmcnt(10)" ::: "memory");
        __builtin_amdgcn_s_barrier();

        const char* Abuf = (const char*)smem + (c & 3) * 16384;
        const char* Bbuf = (const char*)smem + 65536 + (c % 5) * 16384;
        bf16x8 a[4], b[4];
#pragma unroll
        for (int mt = 0; mt < 4; ++mt)
          a[mt] = *(const bf16x8*)(Abuf + (mh * 64 + mt * 16 + lrow) * 128 + kx64);
#pragma unroll
        for (int nt = 0; nt < 4; ++nt)
          b[nt] = *(const bf16x8*)(Bbuf + (nh * 64 + nt * 16 + lrow) * 128 + kx64);
#pragma unroll
        for (int mt = 0; mt < 4; ++mt)
#pragma unroll
          for (int nt = 0; nt < 4; ++nt)
            acc[mt][nt] = __builtin_amdgcn_mfma_f32_16x16x32_bf16(a[mt], b[nt], acc[mt][nt], 0, 0, 0);
      }
    } else {
      // ======== layers 1-3: BK=128 path (16 chunks) ========
      const u16* hin   = hbuf + (u32)((layer - 1) * 2 + (t & 1)) * 262144u + b0 * 64;
      const u16* hprev = hbuf + (u32)(layer * 2 + ((t + 1) & 1)) * 262144u + b0 * 64;

      // A chunk c = K64-images 2c, 2c+1 (c<8: hin; c>=8: hprev), 2x16KB blocks.
      auto issueA = [&](int c, int slot) {
#pragma unroll
        for (int s = 0; s < 2; ++s) {
          int ci = 2 * c + s;  // K64 image index 0..31
          const u16* img = (ci < 16) ? (hin + (u32)ci * 16384u)
                                     : (hprev + (u32)(ci - 16) * 16384u);
          gl_lds16(img + opu0, smem + slot * 16384 + s * 8192 + wave * 1024);
          gl_lds16(img + opu1, smem + slot * 16384 + s * 8192 + wave * 1024 + 512);
        }
      };
      // B chunk c = W images 2c, 2c+1 -> contiguous 32KB; 4 ops/wave.
      auto issueB = [&](int c, int slot) {
        const u16* src = Wsl + (u32)c * 16384u;
#pragma unroll
        for (int q = 0; q < 4; ++q)
          gl_lds16(src + wave * 2048 + q * 512 + lane * 8,
                   smem + 32768 + slot * 16384 + wave * 2048 + q * 512);
      };

      // prologue order: A0, B0, B1 (vmcnt ages derived for uniform vmcnt(4))
      issueA(0, 0);
      issueB(0, 0);
      issueB(1, 1);

      for (int c = 0; c < 16; ++c) {
        // retire chunk c (A(c) youngest needed; only B(c+1) is younger = 4 ops)
        asm volatile("s_waitcnt vmcnt(4)" ::: "memory");
        __builtin_amdgcn_s_barrier();   // one barrier per chunk

        const char* Abuf = (const char*)smem + (c & 1) * 32768 + kh * 16384;
        const char* Bbuf = (const char*)smem + 65536 + (c % 3) * 32768 + kh * 16384;
        bf16x8 a[2][4], b[2][4];
#pragma unroll
        for (int ks = 0; ks < 2; ++ks) {
          const int col = (ks * 64 + kslot) ^ lswz;
#pragma unroll
          for (int mt = 0; mt < 4; ++mt)
            a[ks][mt] = *(const bf16x8*)(Abuf + (mh * 64 + mt * 16 + lrow) * 128 + col);
#pragma unroll
          for (int nt = 0; nt < 4; ++nt)
            b[ks][nt] = *(const bf16x8*)(Bbuf + (nh * 64 + nt * 16 + lrow) * 128 + col);
        }
        // reads retired before issuing DMA into rings (WAR safety w/ 1 barrier)
        asm volatile("s_waitcnt lgkmcnt(0)" ::: "memory");
        {
          int ca = c + 1; int cca = (ca < 16) ? ca : 15;
          issueA(cca, ca & 1);
          int cb = c + 2; int ccb = (cb < 16) ? cb : 15;
          issueB(ccb, cb % 3);
        }
#pragma unroll
        for (int ks = 0; ks < 2; ++ks)
#pragma unroll
          for (int mt = 0; mt < 4; ++mt)
#pragma unroll
            for (int nt = 0; nt < 4; ++nt)
              acc[mt][nt] = __builtin_amdgcn_mfma_f32_16x16x32_bf16(a[ks][mt], b[ks][nt], acc[mt][nt], 0, 0, 0);
      }
    }

    asm volatile("s_waitcnt vmcnt(0)" ::: "memory");  // drain (incl. dummies) before G alias
    __syncthreads();

    // dump gate tiles (16x16 D layout: col=lane&15, row=(lane>>4)*4+r) into G{kh}
    float* Gw = kh ? G1 : G0;
#pragma unroll
    for (int mt = 0; mt < 4; ++mt)
#pragma unroll
      for (int nt = 0; nt < 4; ++nt) {
        int row = mh * 64 + mt * 16 + (lane >> 4) * 4;
        int col = nh * 64 + nt * 16 + (lane & 15);
#pragma unroll
        for (int r = 0; r < 4; ++r) Gw[(row + r) * 132 + col] = acc[mt][nt][r];
      }
    __syncthreads();

    // LSTM cell update; c stays in registers. Gates = G0 + G1 (K-halves) + bias.
    u16* outSlot = hbuf + (u32)(layer * 2 + (t & 1)) * 262144u;
    const int hcol = h0 + nn;
    const int j2 = hcol >> 6;
    const int colin = hcol & 63;
#pragma unroll
    for (int k = 0; k < 8; ++k) {
      int r = r0 + k;
      float gi = G0[r * 132 + nn]      + G1[r * 132 + nn]      + bias_r[0];
      float gf = G0[r * 132 + 32 + nn] + G1[r * 132 + 32 + nn] + bias_r[1];
      float gg = G0[r * 132 + 64 + nn] + G1[r * 132 + 64 + nn] + bias_r[2];
      float go = G0[r * 132 + 96 + nn] + G1[r * 132 + 96 + nn] + bias_r[3];
      float iv = sigm(gi), fv = sigm(gf), gv = tanh_(gg), ov = sigm(go);
      float cv = fv * cst[k] + iv * gv;
      cst[k] = cv;
      float hv = ov * tanh_(cv);
      int b = b0 + r;
      bf16 hb = __float2bfloat16(hv);
      outSlot[j2 * 16384 + b * 64 + (colin ^ ((b & 7) << 3))] = *(u16*)&hb;
      if (layer == 3) {
        out[((size_t)b * TLEN + t) * HDIM + hcol] = hv;
        if (t == TLEN - 1) out[OUT_HT + (size_t)b * HDIM + hcol] = cv;
      }
    }

    // ---- publish: all WG stores done -> release epoch ----
    __syncthreads();
    if (tid == 0)
      __hip_atomic_store(myflag, (u32)(t + 1), __ATOMIC_RELEASE, __HIP_MEMORY_SCOPE_AGENT);
  }
}

// ---------- host ----------

extern "C" void kernel_launch(void* const* d_in, const int* in_sizes, int n_in,
                              void* d_out, int out_size, void* d_ws, size_t ws_size,
                              hipStream_t stream) {
  const float* x = (const float*)d_in[0];
  const float* Wih[4] = {(const float*)d_in[1], (const float*)d_in[5],
                         (const float*)d_in[9], (const float*)d_in[13]};
  const float* Whh[4] = {(const float*)d_in[2], (const float*)d_in[6],
                         (const float*)d_in[10], (const float*)d_in[14]};
  const float* bih[4] = {(const float*)d_in[3], (const float*)d_in[7],
                         (const float*)d_in[11], (const float*)d_in[15]};
  const float* bhh[4] = {(const float*)d_in[4], (const float*)d_in[8],
                         (const float*)d_in[12], (const float*)d_in[16]};

  char* ws = (char*)d_ws;
  bf16* Wp = (bf16*)(ws + WS_WP);
  float* biasc = (float*)(ws + WS_BIAS);
  bf16* xT = (bf16*)(ws + WS_XT);
  u16* hbuf = (u16*)(ws + WS_H);
  u32* flags = (u32*)(ws + WS_FLAGS);
  float* out = (float*)d_out;

  for (int l = 0; l < 4; ++l) {
    int NC = (l == 0) ? 17 : 32;
    int din = (l == 0) ? 64 : 1024;
    bf16* dst = Wp + ((l == 0) ? 0 : (4456448 + (size_t)(l - 1) * 8388608));
    int total = 32 * NC * 128 * 64;
    pack_w<<<(total + 255) / 256, 256, 0, stream>>>(Wih[l], Whh[l], dst, NC, din);
    pack_bias<<<16, 256, 0, stream>>>(bih[l], bhh[l], biasc + l * 4096);
  }
  pack_x<<<(TLEN * BATCH * 64 + 255) / 256, 256, 0, stream>>>(x, xT);
  // zero h ring + flags
  hipMemsetAsync(ws + WS_H, 0, 4194304u + 1024u, stream);

  void* args[] = {(void*)&Wp, (void*)&biasc, (void*)&xT, (void*)&hbuf, (void*)&out, (void*)&flags};
  hipLaunchCooperativeKernel((void*)lstm_main, dim3(256), dim3(512), args, 0, stream);
}